// Round 3
// baseline (302.454 us; speedup 1.0000x reference)
//
#include <hip/hip_runtime.h>
#include <hip/hip_bf16.h>

// PrimaryCaps fused 1x1 convs -> batched GEMM:
//   per n: Out[544,1024] = W[544,512] * X_n[512,1024]
// bf16 MFMA 16x16x32, fp32 accumulate, fp32->bf16 during staging.
// R3: 2-deep software pipeline. Loads for K-chunk c issue at iter c-2 and are
// stored to LDS at iter c-1, so global latency spans a full barrier period.
// The barrier is a raw "s_waitcnt lgkmcnt(0); s_barrier" (NOT __syncthreads,
// which drains vmcnt(0) and would kill the in-flight prefetch).

typedef __attribute__((ext_vector_type(8))) short short8;
typedef __attribute__((ext_vector_type(4))) float f32x4;

#define A_CH   512
#define HW     1024
#define N_B    64
#define O_POSE 512
#define O_ACT  32
#define O_TOT  544
#define TO     128
#define TM     256
#define BK     32
#define NIT    (A_CH / BK)   // 16

__device__ __forceinline__ unsigned pk(float lo, float hi) {
    __hip_bfloat162 h = __float22bfloat162_rn(make_float2(lo, hi));
    return *reinterpret_cast<unsigned*>(&h);
}

// Workgroup barrier that does NOT drain outstanding global loads.
// LDS ops must be complete (lgkmcnt(0)); vmcnt deliberately left alone —
// register-dependency waits (compiler-inserted) handle load consumption.
__device__ __forceinline__ void barrier_keep_loads() {
    asm volatile("s_waitcnt lgkmcnt(0)\n\ts_barrier" ::: "memory");
}

__global__ __launch_bounds__(512, 2) void caps_fused_gemm(
    const float* __restrict__ x,   // [64,512,32,32]
    const float* __restrict__ Wp,  // [512,512]
    const float* __restrict__ bp,  // [512]
    const float* __restrict__ Wa,  // [32,512]
    const float* __restrict__ ba,  // [32]
    float* __restrict__ out)       // poses [64,512,1024] ++ act [64,32,1024]
{
    // bf16 [row][k] tiles, swizzle k' = k ^ (8*((row>>1)&3)); b128 reads and
    // writes stay 16B-aligned; frag reads <=2 lanes/bank (free, m136).
    __shared__ __align__(16) short ldsA[2][TO * BK];  // W tile  16 KB
    __shared__ __align__(16) short ldsB[2][TM * BK];  // X tile  32 KB

    const int tid = threadIdx.x;
    const int n   = blockIdx.z;
    const int o0  = blockIdx.y * TO;
    const int m0  = blockIdx.x * TM;

    const float* xn = x + (size_t)n * A_CH * HW + m0;

    // A (W) staging: o = tid>>2, k8 = (tid&3)*8 -> one b128 LDS write.
    const int ao = tid >> 2;
    const int ak = (tid & 3) * 8;
    const float* arow = nullptr;
    {
        int R = o0 + ao;
        if (R < O_POSE)     arow = Wp + (size_t)R * A_CH + ak;
        else if (R < O_TOT) arow = Wa + (size_t)(R - O_POSE) * A_CH + ak;
    }
    // B (x) staging: m = tid&255, k-half = (tid>>8)*16. 16 k-column dword
    // loads (lane-consecutive m -> coalesced); two b128 LDS writes,
    // measured conflict-free.
    const int bm = tid & 255;
    const int bk = (tid >> 8) * 16;
    const float* bbase = xn + (size_t)bk * HW + bm;

    // 2-deep pipeline register sets
    float4 a0r[2], a1r[2];
    float  br[2][16];

    const int aswz = 8 * ((ao >> 1) & 3);
    const int bswz = 8 * ((bm >> 1) & 3);
    const int aoffW = ao * BK + (ak ^ aswz);
    const int boffW0 = bm * BK + (bk ^ bswz);
    const int boffW1 = bm * BK + ((bk + 8) ^ bswz);

    auto load_tiles = [&](int rs, int k0) {
        if (arow) {
            a0r[rs] = *(const float4*)(arow + k0);
            a1r[rs] = *(const float4*)(arow + k0 + 4);
        } else {
            a0r[rs] = make_float4(0.f, 0.f, 0.f, 0.f);
            a1r[rs] = a0r[rs];
        }
#pragma unroll
        for (int j = 0; j < 16; ++j)
            br[rs][j] = bbase[(size_t)(k0 + j) * HW];
    };

    auto store_tiles = [&](int buf, int rs) {
        short8 av;
        ((unsigned*)&av)[0] = pk(a0r[rs].x, a0r[rs].y);
        ((unsigned*)&av)[1] = pk(a0r[rs].z, a0r[rs].w);
        ((unsigned*)&av)[2] = pk(a1r[rs].x, a1r[rs].y);
        ((unsigned*)&av)[3] = pk(a1r[rs].z, a1r[rs].w);
        *(short8*)&ldsA[buf][aoffW] = av;

        short8 b0, b1;
#pragma unroll
        for (int j = 0; j < 4; ++j) {
            ((unsigned*)&b0)[j] = pk(br[rs][2 * j],     br[rs][2 * j + 1]);
            ((unsigned*)&b1)[j] = pk(br[rs][8 + 2 * j], br[rs][9 + 2 * j]);
        }
        *(short8*)&ldsB[buf][boffW0] = b0;
        *(short8*)&ldsB[buf][boffW1] = b1;
    };

    // wave -> 64(o) x 64(m) quadrant of the 128x256 tile
    const int lane = tid & 63;
    const int w    = tid >> 6;
    const int wo   = (w >> 2) * 64;
    const int wm   = (w & 3) * 64;
    const int l16  = lane & 15;
    const int g    = lane >> 4;

    // iter-invariant frag-read offsets
    int aoffR[4], boffR[4];
#pragma unroll
    for (int f = 0; f < 4; ++f) {
        int r = wo + f * 16 + l16;
        aoffR[f] = r * BK + ((g * 8) ^ (8 * ((r >> 1) & 3)));
        int c = wm + f * 16 + l16;
        boffR[f] = c * BK + ((g * 8) ^ (8 * ((c >> 1) & 3)));
    }

    f32x4 acc[4][4] = {};  // [fo][fm]

    // prologue: chunk0 -> reg0 -> LDS buf0; chunk1 -> reg1 (left in flight)
    load_tiles(0, 0);
    load_tiles(1, BK);
    store_tiles(0, 0);
    barrier_keep_loads();

#pragma unroll
    for (int it = 0; it < NIT; ++it) {
        const int cur = it & 1;
        // issue loads for chunk it+2 into the regset freed last iter
        if (it + 2 < NIT) load_tiles(cur, (it + 2) * BK);

        short8 aF[4], bF[4];
#pragma unroll
        for (int f = 0; f < 4; ++f) {
            aF[f] = *(const short8*)&ldsA[cur][aoffR[f]];
            bF[f] = *(const short8*)&ldsB[cur][boffR[f]];
        }
        // store chunk it+1 (loaded last iter -> latency already covered)
        // into the other buffer; its ds_writes drain under the MFMAs below
        if (it + 1 < NIT) store_tiles(cur ^ 1, (it + 1) & 1);

#pragma unroll
        for (int fo = 0; fo < 4; ++fo)
#pragma unroll
            for (int fm = 0; fm < 4; ++fm)
                acc[fo][fm] = __builtin_amdgcn_mfma_f32_16x16x32_bf16(
                    aF[fo], bF[fm], acc[fo][fm], 0, 0, 0);

        if (it + 1 < NIT) barrier_keep_loads();
    }

    // epilogue: C/D layout col = lane&15, row = (lane>>4)*4 + reg
    float* actOut = out + (size_t)N_B * O_POSE * HW;
    const size_t poseN = (size_t)n * O_POSE * HW;
    const size_t actN  = (size_t)n * O_ACT * HW;
#pragma unroll
    for (int fo = 0; fo < 4; ++fo) {
#pragma unroll
        for (int i = 0; i < 4; ++i) {
            int R = o0 + wo + fo * 16 + g * 4 + i;
            if (R >= O_TOT) continue;
            if (R < O_POSE) {
                float bias = bp[R];
#pragma unroll
                for (int fm = 0; fm < 4; ++fm) {
                    int cc = m0 + wm + fm * 16 + l16;
                    __builtin_nontemporal_store(acc[fo][fm][i] + bias,
                                                &out[poseN + (size_t)R * HW + cc]);
                }
            } else {
                float bias = ba[R - O_POSE];
#pragma unroll
                for (int fm = 0; fm < 4; ++fm) {
                    int cc = m0 + wm + fm * 16 + l16;
                    float v = acc[fo][fm][i] + bias;
                    __builtin_nontemporal_store(1.0f / (1.0f + __expf(-v)),
                                                &actOut[actN + (size_t)(R - O_POSE) * HW + cc]);
                }
            }
        }
    }
}

extern "C" void kernel_launch(void* const* d_in, const int* in_sizes, int n_in,
                              void* d_out, int out_size, void* d_ws, size_t ws_size,
                              hipStream_t stream) {
    (void)in_sizes; (void)n_in; (void)d_ws; (void)ws_size; (void)out_size;
    const float* x  = (const float*)d_in[0];
    const float* Wp = (const float*)d_in[1];
    const float* bp = (const float*)d_in[2];
    const float* Wa = (const float*)d_in[3];
    const float* ba = (const float*)d_in[4];
    dim3 grid(HW / TM, (O_TOT + TO - 1) / TO, N_B);  // (4, 5, 64)
    caps_fused_gemm<<<grid, dim3(512), 0, stream>>>(x, Wp, bp, Wa, ba, (float*)d_out);
}